// Round 4
// baseline (1238.551 us; speedup 1.0000x reference)
//
#include <hip/hip_runtime.h>
#include <math.h>

#define B_ 8
#define L_ 256
#define N_ 22
#define C_ 128
#define H_ 8
#define DK_ 16
#define DFF_ 512
#define NL_ 6
#define MTOK (B_*L_*N_)   // 45056

typedef __bf16 bf16x8 __attribute__((ext_vector_type(8)));
typedef float  f32x4  __attribute__((ext_vector_type(4)));

__device__ __forceinline__ float wave_sum(float v){
#pragma unroll
  for (int i = 32; i >= 1; i >>= 1) v += __shfl_xor(v, i, 64);
  return v;
}

// fast mish: x * tanh(softplus(x)) == x*(t^2+2t)/(t^2+2t+2), t=e^x
__device__ __forceinline__ float mishf(float x){
  float t = __expf(fminf(x, 20.0f));
  float num = t * (t + 2.0f);
  return x * num / (num + 2.0f);
}

// ---------------- positional-encoder kernel: out = x + LN(x + pe) ----------------
__global__ __launch_bounds__(256) void pe_kernel(
    const float* __restrict__ x, const float* __restrict__ g,
    const float* __restrict__ b, float* __restrict__ out)
{
  int row  = (blockIdx.x * 256 + threadIdx.x) >> 6;   // token index
  int lane = threadIdx.x & 63;
  if (row >= MTOK) return;
  int bl = row / N_;            // b*L + l
  int l  = bl & (L_ - 1);
  const float* xr = x + (size_t)row * C_;
  float x0 = xr[lane], x1 = xr[lane + 64];
  int c0 = lane, c1 = lane + 64;
  const float LOG1E4 = 9.210340371976184f;
  float e0 = __expf(LOG1E4 * (-2.0f * (float)c0 / 128.0f));
  float e1 = __expf(LOG1E4 * (-2.0f * (float)c1 / 128.0f));
  float a0 = (float)l * e0, a1 = (float)l * e1;
  float pe0 = (c0 & 1) ? cosf(a0) : sinf(a0);
  float pe1 = (c1 & 1) ? cosf(a1) : sinf(a1);
  float t0 = x0 + pe0, t1 = x1 + pe1;
  float mean = wave_sum(t0 + t1) * (1.0f/128.0f);
  float d0 = t0 - mean, d1 = t1 - mean;
  float var = wave_sum(d0*d0 + d1*d1) * (1.0f/128.0f);
  float inv = rsqrtf(var + 1e-5f);
  float* orow = out + (size_t)row * C_;
  orow[c0] = x0 + d0 * inv * g[c0] + b[c0];
  orow[c1] = x1 + d1 * inv * g[c1] + b[c1];
}

// ---------------- standalone LN (layer-0 entry only): fp32 + bf16 out ----------
__global__ __launch_bounds__(256) void ln_kernel(
    const float* __restrict__ in, const float* __restrict__ g,
    const float* __restrict__ b, float* __restrict__ outf,
    __bf16* __restrict__ outb)
{
  int row  = (blockIdx.x * 256 + threadIdx.x) >> 6;
  int lane = threadIdx.x & 63;
  if (row >= MTOK) return;
  const float* ir = in + (size_t)row * C_;
  float t0 = ir[lane], t1 = ir[lane + 64];
  float mean = wave_sum(t0 + t1) * (1.0f/128.0f);
  float d0 = t0 - mean, d1 = t1 - mean;
  float var = wave_sum(d0*d0 + d1*d1) * (1.0f/128.0f);
  float inv = rsqrtf(var + 1e-5f);
  float v0 = d0 * inv * g[lane]      + b[lane];
  float v1 = d1 * inv * g[lane + 64] + b[lane + 64];
  float* orow = outf + (size_t)row * C_;
  orow[lane]      = v0;
  orow[lane + 64] = v1;
  __bf16* brow = outb + (size_t)row * C_;
  brow[lane]      = (__bf16)v0;
  brow[lane + 64] = (__bf16)v1;
}

// ---------------- weight pack fp32 -> bf16 arena ----------------
#define WQKV_END 589824
#define WO_END   688128
#define W1_END   1081344
#define WTOT     1474560
__global__ __launch_bounds__(256) void wpack_kernel(
    const float* __restrict__ Wq, const float* __restrict__ Wk,
    const float* __restrict__ Wv, const float* __restrict__ Wo,
    const float* __restrict__ W1, const float* __restrict__ W2,
    __bf16* __restrict__ dst)
{
  int i = blockIdx.x * 256 + threadIdx.x;
  float v;
  if (i < WQKV_END) {
    int li = i / 49152, rem = i % 49152;
    int which = rem / 16384, idx = rem % 16384;
    const float* W = which == 0 ? Wq : which == 1 ? Wk : Wv;
    v = W[li * 16384 + idx];
  } else if (i < WO_END) v = Wo[i - WQKV_END];
  else if (i < W1_END)   v = W1[i - WO_END];
  else                   v = W2[i - W1_END];
  dst[i] = (__bf16)v;
}

// pack QKV biases: [NL][384] fp32
__global__ __launch_bounds__(256) void bpack_kernel(
    const float* __restrict__ bq, const float* __restrict__ bk,
    const float* __restrict__ bv, float* __restrict__ dst)
{
  int i = blockIdx.x * 256 + threadIdx.x;   // < NL*384
  int li = i / 384, p = i % 384;
  float v = p < 128 ? bq[li*128 + p] : p < 256 ? bk[li*128 + p - 128] : bv[li*128 + p - 256];
  dst[i] = v;
}

// ---------------- bf16 MFMA GEMM (QKV / Wo+LN_A) --------------------------------
// C[m,n] = sum_k A[m,k]*Bw[n,k]. Tile 128x128, 4 waves (2x2), wave tile 64x64.
// LN: 0 = none (+bias, write bf16)
//     1 = v=acc+bias+res; y=LN(v;g1,b1); outf=y (may alias res), outb=bf16(y)
template<int LN>
__global__ __launch_bounds__(256) void mgemm2(
    const __bf16* __restrict__ A, const __bf16* __restrict__ Bw,
    const float* __restrict__ bias, const float* __restrict__ res,
    __bf16* __restrict__ outb, float* __restrict__ outf,
    const float* __restrict__ g1, const float* __restrict__ b1v,
    int K, int Ntot)
{
  __shared__ __align__(16) char smem[2 * 128 * 256];   // A tile + B tile, 64 KiB
  char* sA = smem;
  char* sB = smem + 128 * 256;

  const int tid  = threadIdx.x;
  const int lane = tid & 63;
  const int wv   = tid >> 6;
  const int l15  = lane & 15;
  const int lh   = lane >> 4;
  const int wm   = wv >> 1;
  const int wn   = wv & 1;
  const int bm   = blockIdx.x * 128;
  const int bn   = blockIdx.y * 128;

  f32x4 acc[4][4] = {};

  for (int k0 = 0; k0 < K; k0 += 128) {
#pragma unroll
    for (int i = 0; i < 8; ++i) {
      int id  = i * 256 + tid;
      int row = id >> 4, c = id & 15;
      int cs  = c ^ (row & 7);
      const char* g = (const char*)(A + (size_t)(bm + row) * K + k0) + cs * 16;
      __builtin_amdgcn_global_load_lds((const unsigned int*)g,
          (unsigned int*)(sA + (size_t)(i * 256 + wv * 64) * 16), 16, 0, 0);
    }
#pragma unroll
    for (int i = 0; i < 8; ++i) {
      int id  = i * 256 + tid;
      int row = id >> 4, c = id & 15;
      int cs  = c ^ (row & 7);
      const char* g = (const char*)(Bw + (size_t)(bn + row) * K + k0) + cs * 16;
      __builtin_amdgcn_global_load_lds((const unsigned int*)g,
          (unsigned int*)(sB + (size_t)(i * 256 + wv * 64) * 16), 16, 0, 0);
    }
    __syncthreads();

#pragma unroll
    for (int kk = 0; kk < 4; ++kk) {
      bf16x8 af[4], bfr[4];
#pragma unroll
      for (int mi = 0; mi < 4; ++mi) {
        int row = wm * 64 + mi * 16 + l15;
        int cs  = (kk * 4 + lh) ^ (row & 7);
        af[mi] = *(const bf16x8*)(sA + row * 256 + cs * 16);
      }
#pragma unroll
      for (int ni = 0; ni < 4; ++ni) {
        int row = wn * 64 + ni * 16 + l15;
        int cs  = (kk * 4 + lh) ^ (row & 7);
        bfr[ni] = *(const bf16x8*)(sB + row * 256 + cs * 16);
      }
#pragma unroll
      for (int mi = 0; mi < 4; ++mi)
#pragma unroll
        for (int ni = 0; ni < 4; ++ni)
          acc[mi][ni] = __builtin_amdgcn_mfma_f32_16x16x32_bf16(
              af[mi], bfr[ni], acc[mi][ni], 0, 0, 0);
    }
    __syncthreads();
  }

  if (LN == 0) {
#pragma unroll
    for (int ni = 0; ni < 4; ++ni) {
      int col = bn + wn * 64 + ni * 16 + l15;
      float bc = bias[col];
#pragma unroll
      for (int mi = 0; mi < 4; ++mi) {
        int rbase = bm + wm * 64 + mi * 16 + lh * 4;
#pragma unroll
        for (int r = 0; r < 4; ++r) {
          float v = acc[mi][ni][r] + bc;
          outb[(size_t)(rbase + r) * Ntot + col] = (__bf16)v;
        }
      }
    }
  } else {
    // fused LN epilogue (Ntot == 128, bn == 0): block owns full rows.
    float* sArr  = (float*)smem;          // [128][2]
    float* s2Arr = sArr + 256;            // [128][2]
    float* mArr  = s2Arr + 256;           // [128]
    float* iArr  = mArr + 128;            // [128]

#pragma unroll
    for (int ni = 0; ni < 4; ++ni) {
      int col = wn * 64 + ni * 16 + l15;
      float bc = bias[col];
#pragma unroll
      for (int mi = 0; mi < 4; ++mi) {
        int Rl = wm * 64 + mi * 16 + lh * 4;
#pragma unroll
        for (int r = 0; r < 4; ++r)
          acc[mi][ni][r] += bc + res[(size_t)(bm + Rl + r) * 128 + col];
      }
    }
#pragma unroll
    for (int mi = 0; mi < 4; ++mi)
#pragma unroll
      for (int r = 0; r < 4; ++r) {
        int Rl = wm * 64 + mi * 16 + lh * 4 + r;
        float s = acc[mi][0][r] + acc[mi][1][r] + acc[mi][2][r] + acc[mi][3][r];
        float q = acc[mi][0][r]*acc[mi][0][r] + acc[mi][1][r]*acc[mi][1][r]
                + acc[mi][2][r]*acc[mi][2][r] + acc[mi][3][r]*acc[mi][3][r];
#pragma unroll
        for (int msk = 1; msk <= 8; msk <<= 1) {
          s += __shfl_xor(s, msk, 64);
          q += __shfl_xor(q, msk, 64);
        }
        if (l15 == 0) { sArr[Rl*2 + wn] = s; s2Arr[Rl*2 + wn] = q; }
      }
    __syncthreads();
    if (tid < 128) {
      float m  = (sArr[tid*2] + sArr[tid*2+1]) * (1.0f/128.0f);
      float vv = (s2Arr[tid*2] + s2Arr[tid*2+1]) * (1.0f/128.0f) - m*m;
      mArr[tid] = m; iArr[tid] = rsqrtf(vv + 1e-5f);
    }
    __syncthreads();
#pragma unroll
    for (int mi = 0; mi < 4; ++mi)
#pragma unroll
      for (int r = 0; r < 4; ++r) {
        int Rl = wm * 64 + mi * 16 + lh * 4 + r;
        float m = mArr[Rl], inv = iArr[Rl];
#pragma unroll
        for (int ni = 0; ni < 4; ++ni) {
          int col = wn * 64 + ni * 16 + l15;
          float y = (acc[mi][ni][r] - m) * inv * g1[col] + b1v[col];
          size_t idx = (size_t)(bm + Rl) * 128 + col;
          outf[idx] = y;
          outb[idx] = (__bf16)y;
        }
      }
  }
}

// ---------------- fused FF residual block: u' = LN_F(z + mish(z@W1^T+b1)@W2^T+b2)
// SECOND=0: write outf/outb = LN_F(...)     (in-layer FF #1)
// SECOND=1: h = LN_F(...); if hout: hout=h; if g2: y=LN(h;g2,b2v) -> outf/outb
// Per 128-row block: 4 chunks of DFF=128. FF1 swapped (mfma(W1,z) -> D[n][m]),
// mid dumped to LDS in frag-native layout, FF2 standard -> accC, fused LN.
// Weights stream directly from global (L2-resident).
template<int SECOND>
__global__ __launch_bounds__(256, 2) void ffuse_kernel(
    const __bf16* __restrict__ zb, const float* __restrict__ resf,
    const __bf16* __restrict__ W1g, const __bf16* __restrict__ W2g,
    const float* __restrict__ b1, const float* __restrict__ b2,
    const float* __restrict__ g1, const float* __restrict__ b1v,
    const float* __restrict__ g2, const float* __restrict__ b2v,
    __bf16* __restrict__ outb, float* __restrict__ outf,
    float* __restrict__ hout)
{
  __shared__ __align__(16) char smem[65536];   // sZ 32K | sMid 32K
  char* sZ   = smem;
  char* sMid = smem + 32768;

  const int tid  = threadIdx.x;
  const int lane = tid & 63;
  const int wv   = tid >> 6;
  const int l15  = lane & 15;
  const int lh   = lane >> 4;
  const int wm   = wv >> 1;
  const int wn   = wv & 1;
  const int bm   = blockIdx.x * 128;

  // stage z tile (std swizzled layout)
#pragma unroll
  for (int i = 0; i < 8; ++i) {
    int id  = i * 256 + tid;
    int row = id >> 4, c = id & 15;
    int cs  = c ^ (row & 7);
    const char* g = (const char*)(zb + (size_t)(bm + row) * 128) + cs * 16;
    __builtin_amdgcn_global_load_lds((const unsigned int*)g,
        (unsigned int*)(sZ + (size_t)(i * 256 + wv * 64) * 16), 16, 0, 0);
  }
  asm volatile("s_waitcnt vmcnt(0)" ::: "memory");
  __syncthreads();

  f32x4 accC[4][4] = {};

  for (int ch = 0; ch < 4; ++ch) {
    // ---- FF1 (swapped): accM[fn][fm] = W1c @ z^T   (D[n][m]) ----
    f32x4 accM[4][4] = {};
#pragma unroll
    for (int ks = 0; ks < 4; ++ks) {
      bf16x8 aw[4], bz[4];
#pragma unroll
      for (int fn = 0; fn < 4; ++fn)
        aw[fn] = *(const bf16x8*)(W1g + (size_t)(ch*128 + wn*64 + fn*16 + l15) * 128
                                   + ks*32 + lh*8);
#pragma unroll
      for (int fm = 0; fm < 4; ++fm) {
        int row = wm * 64 + fm * 16 + l15;
        int cs  = (ks * 4 + lh) ^ (row & 7);
        bz[fm] = *(const bf16x8*)(sZ + row * 256 + cs * 16);
      }
#pragma unroll
      for (int fn = 0; fn < 4; ++fn)
#pragma unroll
        for (int fm = 0; fm < 4; ++fm)
          accM[fn][fm] = __builtin_amdgcn_mfma_f32_16x16x32_bf16(
              aw[fn], bz[fm], accM[fn][fm], 0, 0, 0);
    }
    // bias + mish
#pragma unroll
    for (int fn = 0; fn < 4; ++fn) {
      f32x4 bq = *(const f32x4*)(b1 + ch*128 + wn*64 + fn*16 + lh*4);
#pragma unroll
      for (int fm = 0; fm < 4; ++fm)
#pragma unroll
        for (int r = 0; r < 4; ++r)
          accM[fn][fm][r] = mishf(accM[fn][fm][r] + bq[r]);
    }
    __syncthreads();   // prev FF2 done reading sMid
    // dump mid -> sMid: layout [M1][N1][lh][l15][r] (bf16)
#pragma unroll
    for (int fn = 0; fn < 4; ++fn)
#pragma unroll
      for (int fm = 0; fm < 4; ++fm) {
        int M1 = wm*4 + fm, N1 = wn*4 + fn;
        int addr = (((M1*8 + N1)*4 + lh)*16 + l15) * 8;
        __bf16 h0 = (__bf16)accM[fn][fm][0], h1 = (__bf16)accM[fn][fm][1];
        __bf16 h2 = (__bf16)accM[fn][fm][2], h3 = (__bf16)accM[fn][fm][3];
        uint2 pk;
        pk.x = (unsigned)*(unsigned short*)&h0 | ((unsigned)*(unsigned short*)&h1 << 16);
        pk.y = (unsigned)*(unsigned short*)&h2 | ((unsigned)*(unsigned short*)&h3 << 16);
        *(uint2*)(sMid + addr) = pk;
      }
    __syncthreads();   // dumps visible
    // ---- FF2 (standard): accC[fm][fc] += mid @ W2c^T ----
#pragma unroll
    for (int ks = 0; ks < 4; ++ks) {
      bf16x8 am[4], bw[4];
#pragma unroll
      for (int fm = 0; fm < 4; ++fm) {
        int M1 = wm*4 + fm;
        int a0 = (((M1*8 + (2*ks + (lh>>1)))*4 + ((2*lh)&3))*16 + l15) * 8;
        uint2 lo = *(const uint2*)(sMid + a0);
        uint2 hi = *(const uint2*)(sMid + a0 + 128);
        uint4 u; u.x = lo.x; u.y = lo.y; u.z = hi.x; u.w = hi.y;
        am[fm] = *(bf16x8*)&u;
      }
#pragma unroll
      for (int fc = 0; fc < 4; ++fc)
        bw[fc] = *(const bf16x8*)(W2g + (size_t)(wn*64 + fc*16 + l15) * 512
                                   + ch*128 + ks*32 + lh*8);
#pragma unroll
      for (int fm = 0; fm < 4; ++fm)
#pragma unroll
        for (int fc = 0; fc < 4; ++fc)
          accC[fm][fc] = __builtin_amdgcn_mfma_f32_16x16x32_bf16(
              am[fm], bw[fc], accC[fm][fc], 0, 0, 0);
    }
  }

  // ---- fused LN epilogue over accC (std layout), res = resf ----
  float* sArr  = (float*)sZ;            // overlays sZ (done with it)
  float* s2Arr = sArr + 256;
  float* mArr  = s2Arr + 256;
  float* iArr  = mArr + 128;

#pragma unroll
  for (int fc = 0; fc < 4; ++fc) {
    int col = wn * 64 + fc * 16 + l15;
    float bc = b2[col];
#pragma unroll
    for (int fm = 0; fm < 4; ++fm) {
      int Rl = wm * 64 + fm * 16 + lh * 4;
#pragma unroll
      for (int r = 0; r < 4; ++r)
        accC[fm][fc][r] += bc + resf[(size_t)(bm + Rl + r) * 128 + col];
    }
  }
#pragma unroll
  for (int fm = 0; fm < 4; ++fm)
#pragma unroll
    for (int r = 0; r < 4; ++r) {
      int Rl = wm * 64 + fm * 16 + lh * 4 + r;
      float s = accC[fm][0][r] + accC[fm][1][r] + accC[fm][2][r] + accC[fm][3][r];
      float q = accC[fm][0][r]*accC[fm][0][r] + accC[fm][1][r]*accC[fm][1][r]
              + accC[fm][2][r]*accC[fm][2][r] + accC[fm][3][r]*accC[fm][3][r];
#pragma unroll
      for (int msk = 1; msk <= 8; msk <<= 1) {
        s += __shfl_xor(s, msk, 64);
        q += __shfl_xor(q, msk, 64);
      }
      if (l15 == 0) { sArr[Rl*2 + wn] = s; s2Arr[Rl*2 + wn] = q; }
    }
  __syncthreads();
  if (tid < 128) {
    float m  = (sArr[tid*2] + sArr[tid*2+1]) * (1.0f/128.0f);
    float vv = (s2Arr[tid*2] + s2Arr[tid*2+1]) * (1.0f/128.0f) - m*m;
    mArr[tid] = m; iArr[tid] = rsqrtf(vv + 1e-5f);
  }
  __syncthreads();

  if (SECOND == 0) {
#pragma unroll
    for (int fm = 0; fm < 4; ++fm)
#pragma unroll
      for (int r = 0; r < 4; ++r) {
        int Rl = wm * 64 + fm * 16 + lh * 4 + r;
        float m = mArr[Rl], inv = iArr[Rl];
#pragma unroll
        for (int fc = 0; fc < 4; ++fc) {
          int col = wn * 64 + fc * 16 + l15;
          float y = (accC[fm][fc][r] - m) * inv * g1[col] + b1v[col];
          size_t idx = (size_t)(bm + Rl) * 128 + col;
          outf[idx] = y;
          outb[idx] = (__bf16)y;
        }
      }
  } else {
    // h = LN_F(v); optional hout write; optional second LN (next layer's LN1)
#pragma unroll
    for (int fm = 0; fm < 4; ++fm)
#pragma unroll
      for (int r = 0; r < 4; ++r) {
        int Rl = wm * 64 + fm * 16 + lh * 4 + r;
        float m = mArr[Rl], inv = iArr[Rl];
#pragma unroll
        for (int fc = 0; fc < 4; ++fc) {
          int col = wn * 64 + fc * 16 + l15;
          float h = (accC[fm][fc][r] - m) * inv * g1[col] + b1v[col];
          accC[fm][fc][r] = h;
          if (hout) hout[(size_t)(bm + Rl) * 128 + col] = h;
        }
      }
    if (g2 != nullptr) {
      __syncthreads();
#pragma unroll
      for (int fm = 0; fm < 4; ++fm)
#pragma unroll
        for (int r = 0; r < 4; ++r) {
          int Rl = wm * 64 + fm * 16 + lh * 4 + r;
          float s = accC[fm][0][r] + accC[fm][1][r] + accC[fm][2][r] + accC[fm][3][r];
          float q = accC[fm][0][r]*accC[fm][0][r] + accC[fm][1][r]*accC[fm][1][r]
                  + accC[fm][2][r]*accC[fm][2][r] + accC[fm][3][r]*accC[fm][3][r];
#pragma unroll
          for (int msk = 1; msk <= 8; msk <<= 1) {
            s += __shfl_xor(s, msk, 64);
            q += __shfl_xor(q, msk, 64);
          }
          if (l15 == 0) { sArr[Rl*2 + wn] = s; s2Arr[Rl*2 + wn] = q; }
        }
      __syncthreads();
      if (tid < 128) {
        float m  = (sArr[tid*2] + sArr[tid*2+1]) * (1.0f/128.0f);
        float vv = (s2Arr[tid*2] + s2Arr[tid*2+1]) * (1.0f/128.0f) - m*m;
        mArr[tid] = m; iArr[tid] = rsqrtf(vv + 1e-5f);
      }
      __syncthreads();
#pragma unroll
      for (int fm = 0; fm < 4; ++fm)
#pragma unroll
        for (int r = 0; r < 4; ++r) {
          int Rl = wm * 64 + fm * 16 + lh * 4 + r;
          float m = mArr[Rl], inv = iArr[Rl];
#pragma unroll
          for (int fc = 0; fc < 4; ++fc) {
            int col = wn * 64 + fc * 16 + l15;
            float y = (accC[fm][fc][r] - m) * inv * g2[col] + b2v[col];
            size_t idx = (size_t)(bm + Rl) * 128 + col;
            outf[idx] = y;
            outb[idx] = (__bf16)y;
          }
        }
    }
  }
}

// ---------------- attention over nodes, block per (b,l), scatter-scrambled out ---
__global__ __launch_bounds__(256) void attn_kernel(
    const __bf16* __restrict__ qkv, __bf16* __restrict__ out)
{
  __shared__ float Ks[N_ * C_];
  __shared__ float Vs[N_ * C_];
  int bl = blockIdx.x;            // b*L + l
  int b  = bl >> 8;
  int l  = bl & (L_ - 1);
  size_t mb = (size_t)bl * N_;
  for (int i = threadIdx.x; i < N_ * C_; i += 256) {
    int row = i >> 7, c = i & 127;
    Ks[i] = (float)qkv[(mb + row) * 384 + 128 + c];
    Vs[i] = (float)qkv[(mb + row) * 384 + 256 + c];
  }
  __syncthreads();
  int h  = threadIdx.x >> 5;
  int nq = threadIdx.x & 31;
  if (nq >= N_) return;
  float qr[DK_];
  const __bf16* qp = qkv + (mb + nq) * 384 + h * DK_;
#pragma unroll
  for (int d = 0; d < DK_; ++d) qr[d] = (float)qp[d];
  float sc[N_];
#pragma unroll
  for (int m = 0; m < N_; ++m) {
    float s = 0.0f;
#pragma unroll
    for (int d = 0; d < DK_; ++d) s = fmaf(qr[d], Ks[m*C_ + h*DK_ + d], s);
    sc[m] = s * 0.25f;
  }
  float mx = -1e30f;
#pragma unroll
  for (int m = 0; m < N_; ++m) mx = fmaxf(mx, sc[m]);
  float sum = 0.0f;
#pragma unroll
  for (int m = 0; m < N_; ++m) { sc[m] = __expf(sc[m] - mx); sum += sc[m]; }
  float rs = 1.0f / sum;
  float o[DK_];
#pragma unroll
  for (int d = 0; d < DK_; ++d) o[d] = 0.0f;
#pragma unroll
  for (int m = 0; m < N_; ++m)
#pragma unroll
    for (int d = 0; d < DK_; ++d) o[d] = fmaf(sc[m], Vs[m*C_ + h*DK_ + d], o[d]);
  int flat = nq * L_ + l;
  int l2 = flat / N_;
  int n2 = flat - l2 * N_;
  __bf16* op = out + ((size_t)((b * L_ + l2) * N_ + n2)) * C_ + h * DK_;
#pragma unroll
  for (int d = 0; d < DK_; ++d) op[d] = (__bf16)(o[d] * rs);
}

extern "C" void kernel_launch(void* const* d_in, const int* in_sizes, int n_in,
                              void* d_out, int out_size, void* d_ws, size_t ws_size,
                              hipStream_t stream) {
  const float* x    = (const float*)d_in[0];
  const float* Wq   = (const float*)d_in[1];
  const float* bq   = (const float*)d_in[2];
  const float* Wk   = (const float*)d_in[3];
  const float* bk   = (const float*)d_in[4];
  const float* Wv   = (const float*)d_in[5];
  const float* bv   = (const float*)d_in[6];
  const float* Wo   = (const float*)d_in[7];
  const float* bo   = (const float*)d_in[8];
  const float* W1   = (const float*)d_in[9];
  const float* bf1  = (const float*)d_in[10];
  const float* W2   = (const float*)d_in[11];
  const float* bf2  = (const float*)d_in[12];
  const float* ln1g = (const float*)d_in[13];
  const float* ln1b = (const float*)d_in[14];
  const float* lnAg = (const float*)d_in[15];
  const float* lnAb = (const float*)d_in[16];
  const float* lnFg = (const float*)d_in[17];
  const float* lnFb = (const float*)d_in[18];
  const float* peg  = (const float*)d_in[19];
  const float* peb  = (const float*)d_in[20];

  float* out = (float*)d_out;
  char*  ws  = (char*)d_ws;
  const size_t U = (size_t)MTOK * C_;

  __bf16* wbf   = (__bf16*)ws;                         // 2,949,120 B weight arena
  float*  bqkv  = (float*)(ws + 2949120);              // NL*384*4
  float*  yf    = (float*)(ws + 2958592);              // U*4 fp32 residual/LN base
  __bf16* yb    = (__bf16*)(ws + 2958592 + U*4);       // U*2 bf16 LN out
  __bf16* qkvb  = (__bf16*)(ws + 2958592 + U*6);       // 3U*2 packed QKV
  __bf16* sb    = (__bf16*)(ws + 2958592 + U*12);      // U*2 scrambled attn out

  dim3 blk(256);
  const int lnGrid = MTOK / 4;
  dim3 gqkv(MTOK/128, 3);
  dim3 g128(MTOK/128, 1);

  wpack_kernel<<<WTOT/256, blk, 0, stream>>>(Wq, Wk, Wv, Wo, W1, W2, wbf);
  bpack_kernel<<<NL_*384/256, blk, 0, stream>>>(bq, bk, bv, bqkv);
  pe_kernel<<<lnGrid, blk, 0, stream>>>(x, peg, peb, out);
  ln_kernel<<<lnGrid, blk, 0, stream>>>(out, ln1g, ln1b, yf, yb);

  for (int li = 0; li < NL_; ++li) {
    const __bf16* wqkv_b = wbf + (size_t)li * 49152;
    const __bf16* wo_b   = wbf + WQKV_END + (size_t)li * 16384;
    const __bf16* w1_b   = wbf + WO_END   + (size_t)li * 65536;
    const __bf16* w2_b   = wbf + W1_END   + (size_t)li * 65536;
    const float* bqkv_l = bqkv + (size_t)li * 384;
    const float* bo_l = bo + (size_t)li * 128;
    const float* b1_l = bf1 + (size_t)li * 512;
    const float* b2_l = bf2 + (size_t)li * 128;
    const float* gA = lnAg + (size_t)li * C_; const float* bA = lnAb + (size_t)li * C_;
    const float* gF = lnFg + (size_t)li * C_; const float* bF = lnFb + (size_t)li * C_;
    const float* g1n = (li < NL_-1) ? ln1g + (size_t)(li+1) * C_ : nullptr;
    const float* b1n = (li < NL_-1) ? ln1b + (size_t)(li+1) * C_ : nullptr;

    // QKV = y @ [Wq;Wk;Wv]^T + b
    mgemm2<0><<<gqkv, blk, 0, stream>>>(yb, wqkv_b, bqkv_l, nullptr,
        qkvb, nullptr, nullptr, nullptr, 128, 384);

    // attention + head scramble -> sb
    attn_kernel<<<B_*L_, blk, 0, stream>>>(qkvb, sb);

    // z = LN_A(y + sb@Wo^T + bo): yf/yb in place
    mgemm2<1><<<g128, blk, 0, stream>>>(sb, wo_b, bo_l, yf,
        yb, yf, gA, bA, 128, 128);

    // FF block #1 (fused): u3 = LN_F(z + f(z)) -> yf/yb
    ffuse_kernel<0><<<g128, blk, 0, stream>>>(yb, yf, w1_b, w2_b,
        b1_l, b2_l, gF, bF, nullptr, nullptr, yb, yf, nullptr);

    // FF block #2 (fused): h = LN_F(u3 + f(u3)); y_next = LN1(h) (or h->out at end)
    ffuse_kernel<1><<<g128, blk, 0, stream>>>(yb, yf, w1_b, w2_b,
        b1_l, b2_l, gF, bF, g1n, b1n, yb, yf,
        (li == NL_-1) ? out : nullptr);
  }
  (void)in_sizes; (void)n_in; (void)out_size; (void)ws_size;
}